// Round 9
// baseline (198.813 us; speedup 1.0000x reference)
//
#include <hip/hip_runtime.h>

// Self-attention forward. Inputs f32: x[4,2048,1024], Wqkv[1024,3072],
// bqkv[3072], Wout[1024,1024], bout[1024]; mask[4,2048,2048] int32.
// Output f32 [4,2048,1024].
//
// Round-15: K1 dispatch-tail fix. K1 was 384 wgs at 1 block/CU = 1.5
// rounds on 256 CUs (half the machine idle in round 2; per-tile cost 4600cy
// vs 2483 MFMA content). New gemm192 (BM=256 x BN=192) -> grid 32x16 = 512
// wgs = exactly 2.0 rounds, zero idle. Identical schedule to the proven
// gemm256d (dbuf, stage-ahead, one __syncthreads/tile, T2 swizzle,
// write-combined epilogue); B panel re-laid as one contiguous [192][64]
// region (3 chunks/wave staged, acc[8][3]). K2 stays gemm256d (256 wgs =
// 1.0 round); K4/K5 stay gemm128d (2 blocks/CU).

typedef __attribute__((ext_vector_type(8))) short short8;
typedef __attribute__((ext_vector_type(4))) float f32x4;
typedef unsigned short u16;

#define SEQ 2048
#define NB 4

static __device__ __forceinline__ u16 f2bf(float f) {
    unsigned int u = __builtin_bit_cast(unsigned int, f);
    u += 0x7fffu + ((u >> 16) & 1u);   // RNE
    return (u16)(u >> 16);
}
static __device__ __forceinline__ float bf2f(u16 h) {
    unsigned int u = ((unsigned int)h) << 16;
    return __builtin_bit_cast(float, u);
}

// async global->LDS, 16 bytes/lane. LDS dest = wave-uniform base + lane*16.
static __device__ __forceinline__ void gld16(const u16* l, const u16* g) {
    __builtin_amdgcn_global_load_lds(
        (__attribute__((address_space(1))) void*)(g),
        (__attribute__((address_space(3))) void*)(l),
        16, 0, 0);
}

// f32 -> bf16, 8 elems/thread.
__global__ __launch_bounds__(256) void cvt_bf16(const float* __restrict__ s,
                                                u16* __restrict__ d, long n) {
    long i = ((long)blockIdx.x * 256 + threadIdx.x) * 8;
    if (i >= n) return;
    f32x4 a = *(const f32x4*)(s + i);
    f32x4 b = *(const f32x4*)(s + i + 4);
    short8 o;
    o[0] = (short)f2bf(a.x); o[1] = (short)f2bf(a.y);
    o[2] = (short)f2bf(a.z); o[3] = (short)f2bf(a.w);
    o[4] = (short)f2bf(b.x); o[5] = (short)f2bf(b.y);
    o[6] = (short)f2bf(b.z); o[7] = (short)f2bf(b.w);
    *(short8*)(d + i) = o;
}

// f32 [R][C] -> bf16 [C][R] (transpose + convert), 32x32 LDS tiles.
__global__ __launch_bounds__(256) void transpose_cvt(const float* __restrict__ in,
                                                     u16* __restrict__ out,
                                                     int R, int C) {
    __shared__ float t[32][33];
    const int c0 = blockIdx.x * 32;
    const int r0 = blockIdx.y * 32;
    const int x = threadIdx.x & 31;
    const int y = (threadIdx.x >> 5) * 4;
    #pragma unroll
    for (int i = 0; i < 4; i++)
        t[y + i][x] = in[(long)(r0 + y + i) * C + c0 + x];
    __syncthreads();
    #pragma unroll
    for (int i = 0; i < 4; i++)
        out[(long)(c0 + y + i) * R + r0 + x] = f2bf(t[x][y + i]);
}

// V slice of qkv (per batch [2048 s][1024 d], row stride 3072, col offset 2048)
// -> vt [b][1024 d][2048 s]. bf16 32x32 tile transpose.
__global__ __launch_bounds__(256) void transpose_v(const u16* __restrict__ qkv,
                                                   u16* __restrict__ vt) {
    __shared__ u16 t[32][33];
    const int b = blockIdx.z;
    const int s0 = blockIdx.y * 32;
    const int d0 = blockIdx.x * 32;
    const int x = threadIdx.x & 31;
    const int y = (threadIdx.x >> 5) * 4;
    const u16* src = qkv + (long)b * SEQ * 3072 + 2048;
    u16* dst = vt + (long)b * 1024 * SEQ;
    #pragma unroll
    for (int i = 0; i < 4; i++)
        t[y + i][x] = src[(long)(s0 + y + i) * 3072 + d0 + x];
    __syncthreads();
    #pragma unroll
    for (int i = 0; i < 4; i++)
        dst[(long)(d0 + y + i) * SEQ + s0 + x] = t[x][y + i];
}

// ============================ gemm256d =====================================
// 256x256 tile, BK=64, 512 threads = 8 waves (2M x 4N), per-wave 128x64 out
// = acc[8][4] f32x4. Proven min-2-phase dbuf structure (see round-13).
template<int EPI>
__global__ __launch_bounds__(512) void gemm256d(
    const u16* __restrict__ Ap, long lda, long aBatch,
    const u16* __restrict__ Bp, long ldb, long bBatch,
    void* __restrict__ Cp, long ldc, long cBatch,
    const float* __restrict__ bias, float scale, int K, int nbx)
{
    __shared__ __attribute__((aligned(16))) u16 lds[2][4][8192];

    const int T = K >> 6;              // even
    const int tid = threadIdx.x;
    const int lane = tid & 63;
    const int wave = tid >> 6;
    const int wm = wave >> 2;          // 0..1
    const int wn = wave & 3;           // 0..3
    const int m16 = lane & 15;
    const int quad = lane >> 4;
    const int b = blockIdx.z;

    const int nwg = gridDim.x;
    int wg = blockIdx.x;
    if ((nwg & 7) == 0)
        wg = (wg & 7) * (nwg >> 3) + (wg >> 3);
    const int bx = wg % nbx;
    const int by = wg / nbx;
    const long gm0 = (long)by * 256;
    const long gn0 = (long)bx * 256;

    const u16* A = Ap + (long)b * aBatch;
    const u16* B = Bp + (long)b * bBatch;

    const int rl = lane >> 3;                    // 0..7
    const int lsl = ((lane & 7) ^ rl) * 8;       // pre-swizzled src col (u16)
    const long aR = gm0 + wave * 8 + rl;
    const long bR = gn0 + (wave >> 2) * 64 + (wave & 3) * 8 + rl;

#define STGD(sl, tt) do { \
    const long kc_ = (long)(tt) << 6; \
    u16* l_ = &lds[sl][0][0]; \
    gld16(l_ + 0 * 8192 + wave * 512,       A + (aR)       * lda + kc_ + lsl); \
    gld16(l_ + 0 * 8192 + (8 + wave) * 512, A + (aR + 128) * lda + kc_ + lsl); \
    gld16(l_ + 1 * 8192 + wave * 512,       A + (aR + 64)  * lda + kc_ + lsl); \
    gld16(l_ + 1 * 8192 + (8 + wave) * 512, A + (aR + 192) * lda + kc_ + lsl); \
    gld16(l_ + 2 * 8192 + wave * 512,       B + (bR)       * ldb + kc_ + lsl); \
    gld16(l_ + 2 * 8192 + (8 + wave) * 512, B + (bR + 128) * ldb + kc_ + lsl); \
    gld16(l_ + 3 * 8192 + wave * 512,       B + (bR + 32)  * ldb + kc_ + lsl); \
    gld16(l_ + 3 * 8192 + (8 + wave) * 512, B + (bR + 160) * ldb + kc_ + lsl); \
} while (0)

    const int s0 = quad ^ (m16 & 7);
    const int aBase = (wm * 64 + m16) * 64;
    const int bBase = (wn * 32 + m16) * 64;
    const int aoff0 = aBase + s0 * 8, aoff1 = aBase + (s0 ^ 4) * 8;
    const int boff0 = bBase + s0 * 8, boff1 = bBase + (s0 ^ 4) * 8;

    short8 aF[4][2], b0F[2][2], b1F[2][2];
    f32x4 acc[8][4];
    #pragma unroll
    for (int mi = 0; mi < 8; mi++)
        #pragma unroll
        for (int ni = 0; ni < 4; ni++)
            acc[mi][ni] = (f32x4){0.f, 0.f, 0.f, 0.f};

#define TILE_COMPUTE(sl) do { \
    const u16* l = &lds[sl][0][0]; \
    _Pragma("unroll") \
    for (int mfl = 0; mfl < 4; ++mfl) { \
        aF[mfl][0] = *(const short8*)(l + aoff0 + mfl * 1024); \
        aF[mfl][1] = *(const short8*)(l + aoff1 + mfl * 1024); \
    } \
    _Pragma("unroll") \
    for (int nj = 0; nj < 2; ++nj) { \
        b0F[nj][0] = *(const short8*)(l + 2 * 8192 + boff0 + nj * 1024); \
        b0F[nj][1] = *(const short8*)(l + 2 * 8192 + boff1 + nj * 1024); \
        b1F[nj][0] = *(const short8*)(l + 3 * 8192 + boff0 + nj * 1024); \
        b1F[nj][1] = *(const short8*)(l + 3 * 8192 + boff1 + nj * 1024); \
    } \
    _Pragma("unroll") \
    for (int mi = 0; mi < 4; ++mi) \
        _Pragma("unroll") \
        for (int nj = 0; nj < 4; ++nj) { \
            const short8* bf = (nj < 2) ? &b0F[nj][0] : &b1F[nj - 2][0]; \
            acc[mi][nj] = __builtin_amdgcn_mfma_f32_16x16x32_bf16( \
                aF[mi][0], bf[0], acc[mi][nj], 0, 0, 0); \
            acc[mi][nj] = __builtin_amdgcn_mfma_f32_16x16x32_bf16( \
                aF[mi][1], bf[1], acc[mi][nj], 0, 0, 0); \
        } \
    _Pragma("unroll") \
    for (int mfl = 0; mfl < 4; ++mfl) { \
        aF[mfl][0] = *(const short8*)(l + 1 * 8192 + aoff0 + mfl * 1024); \
        aF[mfl][1] = *(const short8*)(l + 1 * 8192 + aoff1 + mfl * 1024); \
    } \
    _Pragma("unroll") \
    for (int mi = 0; mi < 4; ++mi) \
        _Pragma("unroll") \
        for (int nj = 0; nj < 4; ++nj) { \
            const short8* bf = (nj < 2) ? &b0F[nj][0] : &b1F[nj - 2][0]; \
            acc[4 + mi][nj] = __builtin_amdgcn_mfma_f32_16x16x32_bf16( \
                aF[mi][0], bf[0], acc[4 + mi][nj], 0, 0, 0); \
            acc[4 + mi][nj] = __builtin_amdgcn_mfma_f32_16x16x32_bf16( \
                aF[mi][1], bf[1], acc[4 + mi][nj], 0, 0, 0); \
        } \
} while (0)

    STGD(0, 0);
    __syncthreads();

    for (int t = 0; t < T; t += 2) {
        if (t + 1 < T) STGD(1, t + 1);
        TILE_COMPUTE(0);
        __syncthreads();
        if (t + 2 < T) STGD(0, t + 2);
        TILE_COMPUTE(1);
        __syncthreads();
    }

    const long row0 = gm0 + wm * 128 + quad * 4;
    const long colbase = gn0 + wn * 64 + m16;
    if (EPI == 0 || EPI == 1) {
        u16* C = (u16*)Cp + (long)b * cBatch;
        float bv[4];
        #pragma unroll
        for (int ni = 0; ni < 4; ++ni)
            bv[ni] = (EPI == 0 && bias)
                   ? bias[colbase + (ni >> 1) * 32 + (ni & 1) * 16] : 0.f;
        #pragma unroll
        for (int mi = 0; mi < 8; ++mi) {
            const long rb = row0 + (mi >> 2) * 64 + (mi & 3) * 16;
            #pragma unroll
            for (int r = 0; r < 4; ++r) {
                u16* Crow = C + (rb + r) * ldc + colbase;
                #pragma unroll
                for (int ni = 0; ni < 4; ++ni) {
                    const float vv = (EPI == 1) ? acc[mi][ni][r] * scale
                                                : acc[mi][ni][r] + bv[ni];
                    Crow[(ni >> 1) * 32 + (ni & 1) * 16] = f2bf(vv);
                }
            }
        }
    } else {
        float* C = (float*)Cp + (long)b * cBatch;
        float bv[4];
        #pragma unroll
        for (int ni = 0; ni < 4; ++ni)
            bv[ni] = bias ? bias[colbase + (ni >> 1) * 32 + (ni & 1) * 16] : 0.f;
        #pragma unroll
        for (int mi = 0; mi < 8; ++mi) {
            const long rb = row0 + (mi >> 2) * 64 + (mi & 3) * 16;
            #pragma unroll
            for (int r = 0; r < 4; ++r) {
                float* Crow = C + (rb + r) * ldc + colbase;
                #pragma unroll
                for (int ni = 0; ni < 4; ++ni)
                    Crow[(ni >> 1) * 32 + (ni & 1) * 16] = acc[mi][ni][r] + bv[ni];
            }
        }
    }
#undef STGD
#undef TILE_COMPUTE
}

// ============================ gemm192 ======================================
// 256x192 tile, BK=64, 512 threads = 8 waves (2M x 4N), per-wave 128x48 out
// = acc[8][3] f32x4. Same schedule as gemm256d. LDS per buffer 56 KiB:
// [0,8192) A rows {0-63,128-191}, [8192,16384) A rows {64-127,192-255}
// (identical to gemm256d's A layout), [16384,28672) B rows 0-191 contiguous
// (chunk c = i*8+wave covers rows 8c..8c+7). Wave wn owns cols wn*48..+47.
// Grid for K1: 32x16 = 512 wgs = exactly 2.0 rounds at 1 block/CU.
template<int EPI>
__global__ __launch_bounds__(512) void gemm192(
    const u16* __restrict__ Ap, long lda, long aBatch,
    const u16* __restrict__ Bp, long ldb, long bBatch,
    void* __restrict__ Cp, long ldc, long cBatch,
    const float* __restrict__ bias, float scale, int K, int nbx)
{
    __shared__ __attribute__((aligned(16))) u16 lds[2][28672];

    const int T = K >> 6;              // even
    const int tid = threadIdx.x;
    const int lane = tid & 63;
    const int wave = tid >> 6;
    const int wm = wave >> 2;          // 0..1
    const int wn = wave & 3;           // 0..3
    const int m16 = lane & 15;
    const int quad = lane >> 4;
    const int b = blockIdx.z;

    const int nwg = gridDim.x;
    int wg = blockIdx.x;
    if ((nwg & 7) == 0)
        wg = (wg & 7) * (nwg >> 3) + (wg >> 3);
    const int bx = wg % nbx;
    const int by = wg / nbx;
    const long gm0 = (long)by * 256;
    const long gn0 = (long)bx * 192;

    const u16* A = Ap + (long)b * aBatch;
    const u16* B = Bp + (long)b * bBatch;

    const int rl = lane >> 3;                    // 0..7
    const int lsl = ((lane & 7) ^ rl) * 8;       // pre-swizzled src col (u16)
    const long aR = gm0 + wave * 8 + rl;
    const long bR = gn0 + wave * 8 + rl;         // + i*64, i<3

#define STG192(sl, tt) do { \
    const long kc_ = (long)(tt) << 6; \
    u16* l_ = &lds[sl][0]; \
    gld16(l_ + wave * 512,              A + (aR)       * lda + kc_ + lsl); \
    gld16(l_ + (8 + wave) * 512,        A + (aR + 128) * lda + kc_ + lsl); \
    gld16(l_ + 8192 + wave * 512,       A + (aR + 64)  * lda + kc_ + lsl); \
    gld16(l_ + 8192 + (8 + wave) * 512, A + (aR + 192) * lda + kc_ + lsl); \
    gld16(l_ + 16384 + wave * 512,        B + (bR)       * ldb + kc_ + lsl); \
    gld16(l_ + 16384 + (8 + wave) * 512,  B + (bR + 64)  * ldb + kc_ + lsl); \
    gld16(l_ + 16384 + (16 + wave) * 512, B + (bR + 128) * ldb + kc_ + lsl); \
} while (0)

    const int s0 = quad ^ (m16 & 7);
    const int aBase = (wm * 64 + m16) * 64;
    const int bBase = (wn * 48 + m16) * 64;
    const int aoff0 = aBase + s0 * 8, aoff1 = aBase + (s0 ^ 4) * 8;
    const int boff0 = bBase + s0 * 8, boff1 = bBase + (s0 ^ 4) * 8;

    short8 aF[4][2], bF[3][2];
    f32x4 acc[8][3];
    #pragma unroll
    for (int mi = 0; mi < 8; mi++)
        #pragma unroll
        for (int ni = 0; ni < 3; ni++)
            acc[mi][ni] = (f32x4){0.f, 0.f, 0.f, 0.f};

#define TILE192(sl) do { \
    const u16* l = &lds[sl][0]; \
    _Pragma("unroll") \
    for (int mfl = 0; mfl < 4; ++mfl) { \
        aF[mfl][0] = *(const short8*)(l + aoff0 + mfl * 1024); \
        aF[mfl][1] = *(const short8*)(l + aoff1 + mfl * 1024); \
    } \
    _Pragma("unroll") \
    for (int nj = 0; nj < 3; ++nj) { \
        bF[nj][0] = *(const short8*)(l + 16384 + boff0 + nj * 1024); \
        bF[nj][1] = *(const short8*)(l + 16384 + boff1 + nj * 1024); \
    } \
    _Pragma("unroll") \
    for (int mi = 0; mi < 4; ++mi) \
        _Pragma("unroll") \
        for (int nj = 0; nj < 3; ++nj) { \
            acc[mi][nj] = __builtin_amdgcn_mfma_f32_16x16x32_bf16( \
                aF[mi][0], bF[nj][0], acc[mi][nj], 0, 0, 0); \
            acc[mi][nj] = __builtin_amdgcn_mfma_f32_16x16x32_bf16( \
                aF[mi][1], bF[nj][1], acc[mi][nj], 0, 0, 0); \
        } \
    _Pragma("unroll") \
    for (int mfl = 0; mfl < 4; ++mfl) { \
        aF[mfl][0] = *(const short8*)(l + 8192 + aoff0 + mfl * 1024); \
        aF[mfl][1] = *(const short8*)(l + 8192 + aoff1 + mfl * 1024); \
    } \
    _Pragma("unroll") \
    for (int mi = 0; mi < 4; ++mi) \
        _Pragma("unroll") \
        for (int nj = 0; nj < 3; ++nj) { \
            acc[4 + mi][nj] = __builtin_amdgcn_mfma_f32_16x16x32_bf16( \
                aF[mi][0], bF[nj][0], acc[4 + mi][nj], 0, 0, 0); \
            acc[4 + mi][nj] = __builtin_amdgcn_mfma_f32_16x16x32_bf16( \
                aF[mi][1], bF[nj][1], acc[4 + mi][nj], 0, 0, 0); \
        } \
} while (0)

    STG192(0, 0);
    __syncthreads();

    for (int t = 0; t < T; t += 2) {
        if (t + 1 < T) STG192(1, t + 1);
        TILE192(0);
        __syncthreads();
        if (t + 2 < T) STG192(0, t + 2);
        TILE192(1);
        __syncthreads();
    }

    // epilogue (write-combined): rows gm0+wm*128+(mi>>2)*64+(mi&3)*16+quad*4+r,
    // cols gn0+wn*48+nj*16+m16.
    const long row0 = gm0 + wm * 128 + quad * 4;
    const long colbase = gn0 + wn * 48 + m16;
    if (EPI == 0 || EPI == 1) {
        u16* C = (u16*)Cp + (long)b * cBatch;
        float bv[3];
        #pragma unroll
        for (int ni = 0; ni < 3; ++ni)
            bv[ni] = (EPI == 0 && bias) ? bias[colbase + ni * 16] : 0.f;
        #pragma unroll
        for (int mi = 0; mi < 8; ++mi) {
            const long rb = row0 + (mi >> 2) * 64 + (mi & 3) * 16;
            #pragma unroll
            for (int r = 0; r < 4; ++r) {
                u16* Crow = C + (rb + r) * ldc + colbase;
                #pragma unroll
                for (int ni = 0; ni < 3; ++ni) {
                    const float vv = (EPI == 1) ? acc[mi][ni][r] * scale
                                                : acc[mi][ni][r] + bv[ni];
                    Crow[ni * 16] = f2bf(vv);
                }
            }
        }
    } else {
        float* C = (float*)Cp + (long)b * cBatch;
        float bv[3];
        #pragma unroll
        for (int ni = 0; ni < 3; ++ni)
            bv[ni] = bias ? bias[colbase + ni * 16] : 0.f;
        #pragma unroll
        for (int mi = 0; mi < 8; ++mi) {
            const long rb = row0 + (mi >> 2) * 64 + (mi & 3) * 16;
            #pragma unroll
            for (int r = 0; r < 4; ++r) {
                float* Crow = C + (rb + r) * ldc + colbase;
                #pragma unroll
                for (int ni = 0; ni < 3; ++ni)
                    Crow[ni * 16] = acc[mi][ni][r] + bv[ni];
            }
        }
    }
#undef STG192
#undef TILE192
}

// ============================ gemm128d =====================================
// 128x128 tile, BK=64, 4 waves, 64 KiB LDS -> 2 blocks/CU (K4/K5).
template<int EPI>
__global__ __launch_bounds__(256, 2) void gemm128d(
    const u16* __restrict__ Ap, long lda, long aBatch,
    const u16* __restrict__ Bp, long ldb, long bBatch,
    void* __restrict__ Cp, long ldc, long cBatch,
    const float* __restrict__ bias, float scale, int K, int nbx)
{
    __shared__ __attribute__((aligned(16))) u16 lds[2][2][8192];

    const int T = K >> 6;              // even
    const int tid = threadIdx.x;
    const int lane = tid & 63;
    const int wave = tid >> 6;         // 0..3
    const int wm = wave >> 1;          // 0..1
    const int wn = wave & 1;           // 0..1
    const int m16 = lane & 15;
    const int quad = lane >> 4;
    const int b = blockIdx.z;

    const int nwg = gridDim.x;
    int wg = blockIdx.x;
    if ((nwg & 7) == 0)
        wg = (wg & 7) * (nwg >> 3) + (wg >> 3);
    const int bx = wg % nbx;
    const int by = wg / nbx;
    const long m0 = (long)by * 128;
    const long n0 = (long)bx * 128;

    const u16* A = Ap + (long)b * aBatch;
    const u16* B = Bp + (long)b * bBatch;

    const int rl = lane >> 3;                 // 0..7
    const int lsl = ((lane & 7) ^ rl) * 8;    // pre-swizzled src col (u16)
    const long aR = m0 + wave * 8 + rl;       // + i*32
    const long bR = n0 + wave * 8 + rl;       // + i*32

#define STG128(sl, tt) do { \
    const long kc_ = (long)(tt) << 6; \
    _Pragma("unroll") \
    for (int i_ = 0; i_ < 4; ++i_) { \
        gld16(&lds[sl][0][(i_ * 4 + wave) * 512], A + (aR + i_ * 32) * lda + kc_ + lsl); \
        gld16(&lds[sl][1][(i_ * 4 + wave) * 512], B + (bR + i_ * 32) * ldb + kc_ + lsl); \
    } \
} while (0)

    const int s0 = quad ^ (m16 & 7);
    const int aoff0 = (wm * 64 + m16) * 64 + s0 * 8;
    const int aoff1 = (wm * 64 + m16) * 64 + (s0 ^ 4) * 8;
    const int boff0 = (wn * 64 + m16) * 64 + s0 * 8;
    const int boff1 = (wn * 64 + m16) * 64 + (s0 ^ 4) * 8;

    short8 aF[4][2], bF[4][2];
    f32x4 acc[4][4];
    #pragma unroll
    for (int mi = 0; mi < 4; mi++)
        #pragma unroll
        for (int ni = 0; ni < 4; ni++)
            acc[mi][ni] = (f32x4){0.f, 0.f, 0.f, 0.f};

#define TILE128(sl) do { \
    const u16* la = &lds[sl][0][0]; \
    const u16* lb = &lds[sl][1][0]; \
    _Pragma("unroll") \
    for (int mf = 0; mf < 4; ++mf) { \
        aF[mf][0] = *(const short8*)(la + aoff0 + mf * 1024); \
        aF[mf][1] = *(const short8*)(la + aoff1 + mf * 1024); \
    } \
    _Pragma("unroll") \
    for (int nj = 0; nj < 4; ++nj) { \
        bF[nj][0] = *(const short8*)(lb + boff0 + nj * 1024); \
        bF[nj][1] = *(const short8*)(lb + boff1 + nj * 1024); \
    } \
    _Pragma("unroll") \
    for (int mi = 0; mi < 4; ++mi) \
        _Pragma("unroll") \
        for (int nj = 0; nj < 4; ++nj) { \
            acc[mi][nj] = __builtin_amdgcn_mfma_f32_16x16x32_bf16( \
                aF[mi][0], bF[nj][0], acc[mi][nj], 0, 0, 0); \
            acc[mi][nj] = __builtin_amdgcn_mfma_f32_16x16x32_bf16( \
                aF[mi][1], bF[nj][1], acc[mi][nj], 0, 0, 0); \
        } \
} while (0)

    STG128(0, 0);
    __syncthreads();

    for (int t = 0; t < T; t += 2) {
        if (t + 1 < T) STG128(1, t + 1);
        TILE128(0);
        __syncthreads();
        if (t + 2 < T) STG128(0, t + 2);
        TILE128(1);
        __syncthreads();
    }

    const long row0 = m0 + wm * 64 + quad * 4;
    const long colbase = n0 + wn * 64 + m16;
    if (EPI == 0 || EPI == 1) {
        u16* C = (u16*)Cp + (long)b * cBatch;
        float bv[4];
        #pragma unroll
        for (int ni = 0; ni < 4; ++ni)
            bv[ni] = (EPI == 0 && bias) ? bias[colbase + ni * 16] : 0.f;
        #pragma unroll
        for (int mi = 0; mi < 4; ++mi)
            #pragma unroll
            for (int r = 0; r < 4; ++r) {
                u16* Crow = C + (row0 + mi * 16 + r) * ldc + colbase;
                #pragma unroll
                for (int ni = 0; ni < 4; ++ni) {
                    const float vv = (EPI == 1) ? acc[mi][ni][r] * scale
                                                : acc[mi][ni][r] + bv[ni];
                    Crow[ni * 16] = f2bf(vv);
                }
            }
    } else {
        float* C = (float*)Cp + (long)b * cBatch;
        float bv[4];
        #pragma unroll
        for (int ni = 0; ni < 4; ++ni)
            bv[ni] = bias ? bias[colbase + ni * 16] : 0.f;
        #pragma unroll
        for (int mi = 0; mi < 4; ++mi)
            #pragma unroll
            for (int r = 0; r < 4; ++r) {
                float* Crow = C + (row0 + mi * 16 + r) * ldc + colbase;
                #pragma unroll
                for (int ni = 0; ni < 4; ++ni)
                    Crow[ni * 16] = acc[mi][ni][r] + bv[ni];
            }
    }
#undef STG128
#undef TILE128
}

// in-place masked row softmax over 2048 bf16 (f32 math). 1 block per row.
// mask==0 -> score := 1e-10 (applied here in f32; coalesced uint4 reads).
__global__ __launch_bounds__(256) void softmax2048(u16* __restrict__ S,
                                                   const int* __restrict__ mask) {
    const long row = blockIdx.x;
    u16* p = S + row * SEQ;
    const int* mrow = mask + row * SEQ;
    const int tid = threadIdx.x;

    short8 v = *(const short8*)(p + tid * 8);
    uint4 mw0 = *(const uint4*)(mrow + tid * 8);
    uint4 mw1 = *(const uint4*)(mrow + tid * 8 + 4);
    const unsigned int* mwv = (const unsigned int*)&mw0;

    float f[8];
    #pragma unroll
    for (int j = 0; j < 8; j++) {
        const unsigned int mv = (j < 4) ? mwv[j] : ((const unsigned int*)&mw1)[j - 4];
        f[j] = (mv == 0u) ? 1e-10f : bf2f((u16)v[j]);
    }

    float m = f[0];
    #pragma unroll
    for (int j = 1; j < 8; j++) m = fmaxf(m, f[j]);
    #pragma unroll
    for (int i = 1; i < 64; i <<= 1) m = fmaxf(m, __shfl_xor(m, i));

    __shared__ float redm[4], reds[4];
    if ((tid & 63) == 0) redm[tid >> 6] = m;
    __syncthreads();
    m = fmaxf(fmaxf(redm[0], redm[1]), fmaxf(redm[2], redm[3]));

    float e[8], s = 0.f;
    #pragma unroll
    for (int j = 0; j < 8; j++) { e[j] = __expf(f[j] - m); s += e[j]; }
    #pragma unroll
    for (int i = 1; i < 64; i <<= 1) s += __shfl_xor(s, i);
    if ((tid & 63) == 0) reds[tid >> 6] = s;
    __syncthreads();
    s = reds[0] + reds[1] + reds[2] + reds[3];

    const float inv = 1.f / s;
    short8 o;
    #pragma unroll
    for (int j = 0; j < 8; j++) o[j] = (short)f2bf(e[j] * inv);
    *(short8*)(p + tid * 8) = o;
}

extern "C" void kernel_launch(void* const* d_in, const int* in_sizes, int n_in,
                              void* d_out, int out_size, void* d_ws, size_t ws_size,
                              hipStream_t stream) {
    const float* x    = (const float*)d_in[0];
    const int*   mask = (const int*)d_in[1];
    const float* Wqkv = (const float*)d_in[2];
    const float* bqkv = (const float*)d_in[3];
    const float* Wout = (const float*)d_in[4];
    const float* bout = (const float*)d_in[5];
    float* out = (float*)d_out;

    char* ws = (char*)d_ws;
    // ws layout, total 102,760,448 bytes:
    //   [0,        16777216) xh  bf16 [8192][1024]          (cvt -> K1)
    //   [16777216, 23068672) wqt bf16 [3072][1024]          (cvt -> K1)
    //   [0,        33554432) sc  bf16 [4][2048][2048]       (K2 -> K4; xh,wqt dead)
    //   [33554432, 35651584) wot bf16 [1024][1024]          (cvt -> K5)
    //   [35651584, 85983232) qkv bf16 [8192][3072]          (K1 -> K2)
    //   [35651584, 52428800) attn bf16 [8192][1024]         (K4 -> K5; qkv dead)
    //   [85983232,102760448) vt  bf16 [4][1024][2048]       (transpose_v -> K4)
    u16* xh   = (u16*)(ws + 0);
    u16* wqt  = (u16*)(ws + 16777216);
    u16* sc   = (u16*)(ws + 0);
    u16* wot  = (u16*)(ws + 33554432);
    u16* qkv  = (u16*)(ws + 35651584);
    u16* attn = (u16*)(ws + 35651584);
    u16* vt   = (u16*)(ws + 85983232);

    cvt_bf16<<<4096, 256, 0, stream>>>(x, xh, 8388608);
    transpose_cvt<<<dim3(96, 32), 256, 0, stream>>>(Wqkv, wqt, 1024, 3072);
    transpose_cvt<<<dim3(32, 32), 256, 0, stream>>>(Wout, wot, 1024, 1024);

    // K1: qkv = x @ Wqkv + bqkv (M=8192, N=3072, K=1024), bf16 out.
    // gemm192 (256x192): grid 16x32 = 512 wgs = 2.0 exact rounds, nbx=16.
    gemm192<0><<<dim3(512, 1, 1), 512, 0, stream>>>(
        xh, 1024, 0, wqt, 1024, 0, qkv, 3072, 0, bqkv, 1.f, 1024, 16);

    // V slice -> vt [b][d][s]
    transpose_v<<<dim3(32, 64, NB), 256, 0, stream>>>(qkv, vt);

    // K2: sc[b] = (Q[b] @ K[b]^T)/32 (M=N=2048, K=1024), bf16 out.
    // gemm256d: 8x8 = 64 wgs/batch x 4 = 256 wgs = 1.0 round.
    gemm256d<1><<<dim3(64, 1, NB), 512, 0, stream>>>(
        qkv, 3072, (long)SEQ * 3072, qkv + 1024, 3072, (long)SEQ * 3072,
        sc, SEQ, (long)SEQ * SEQ, nullptr, 0.03125f, 1024, 8);

    // K3: masked softmax rows (mask==0 -> 1e-10, f32 math, bf16 storage)
    softmax2048<<<dim3(NB * SEQ), 256, 0, stream>>>(sc, mask);

    // K4: attn[b] = P[b] @ V[b] (M=2048, N=1024, K=2048), bf16 out.
    // gemm128d: 8x16 = 128 wgs/batch x 4 = 512 wgs = 2 blocks/CU.
    gemm128d<0><<<dim3(128, 1, NB), 256, 0, stream>>>(
        sc, SEQ, (long)SEQ * SEQ, vt, SEQ, (long)1024 * SEQ,
        attn, 1024, (long)SEQ * 1024, nullptr, 1.f, 2048, 8);

    // K5: out = attn @ Wout + bout (M=8192, N=1024, K=1024), f32 out.
    // gemm128d: 8x64 = 512 wgs = 2 blocks/CU.
    gemm128d<2><<<dim3(512, 1, 1), 256, 0, stream>>>(
        attn, 1024, 0, wot, 1024, 0, out, 1024, 0, bout, 1.f, 1024, 8);
}